// Round 1
// baseline (300.544 us; speedup 1.0000x reference)
//
#include <hip/hip_runtime.h>

// Firefly optimizer on MI355X.
// species=4, pop=4096, dim=16, steps = noise_elems / firefly_elems (=4).
// Per step: costs -> pairwise W -> attraction -> update+clip (+mix at step%25==0).
// Pairwise is VALU-bound; exp(-d2) is ~0 for almost all pairs (typ. d2~171),
// so a wave-uniform __any(d2<25 && mask) skip removes exp+accumulation for
// ~99.9% of iterations (skipped terms contribute < 1e-7, threshold is 8e-2).

#define SPECIES 4
#define POP     4096
#define DIM     16
#define NSI     (SPECIES * POP)   // 16384 fireflies total
#define NCOMP   17                // 16 acc dims + wsum
#define ITILE   256               // i-fireflies per block (1 per thread)

__device__ __forceinline__ float seg16_sum(float v) {
    // sum across 16-lane segments (threads of one firefly, d = lane & 15)
    v += __shfl_xor(v, 1, 16);
    v += __shfl_xor(v, 2, 16);
    v += __shfl_xor(v, 4, 16);
    v += __shfl_xor(v, 8, 16);
    return v;
}

// ---- initial cost/sq from x ------------------------------------------------
__global__ void cost_kernel(const float* __restrict__ x,
                            float* __restrict__ sq, float* __restrict__ cost) {
    int t  = blockIdx.x * blockDim.x + threadIdx.x;   // 0 .. NSI*DIM-1
    int si = t >> 4;
    int d  = t & 15;
    float xv = x[t];
    float s1 = xv * xv;
    float c  = cospif(2.0f * xv);                     // cos(2*pi*x), accurate
    float s1t = seg16_sum(s1);
    float ct  = seg16_sum(c);
    if (d == 0) {
        sq[si]   = s1t;
        cost[si] = 10.0f * DIM + s1t - 10.0f * ct;
    }
}

// ---- pairwise attraction partials -----------------------------------------
// grid: (POP/ITILE, JC, SPECIES), block: 256 (one i per thread).
// partial layout: [jc][si][NCOMP]
template <int JC>
__global__ __launch_bounds__(256) void pair_kernel(
        const float* __restrict__ x,
        const float* __restrict__ sq, const float* __restrict__ cost,
        float* __restrict__ partial) {
    constexpr int JT = POP / JC;                      // j's per chunk
    __shared__ float xj_s[JT][DIM];
    __shared__ float sq_s[JT];
    __shared__ float c_s[JT];

    const int s  = blockIdx.z;
    const int j0 = blockIdx.y * JT;
    const int t  = threadIdx.x;

    // stage j-tile
    for (int jj = t; jj < JT; jj += 256) {
        const int j = j0 + jj;
        const float4* src = (const float4*)&x[((size_t)s * POP + j) * DIM];
        float4* dst = (float4*)&xj_s[jj][0];
        dst[0] = src[0]; dst[1] = src[1]; dst[2] = src[2]; dst[3] = src[3];
        sq_s[jj] = sq[s * POP + j];
        c_s[jj]  = cost[s * POP + j];
    }
    __syncthreads();

    const int i = blockIdx.x * ITILE + t;
    const size_t ib = ((size_t)s * POP + i) * DIM;
    float xi[DIM];
    #pragma unroll
    for (int d = 0; d < DIM; d += 4) {
        float4 v = *(const float4*)&x[ib + d];
        xi[d] = v.x; xi[d + 1] = v.y; xi[d + 2] = v.z; xi[d + 3] = v.w;
    }
    const float sqi = sq[s * POP + i];
    const float ci  = cost[s * POP + i];

    float acc[DIM];
    #pragma unroll
    for (int d = 0; d < DIM; ++d) acc[d] = 0.0f;
    float wsum = 0.0f;

    for (int jj = 0; jj < JT; ++jj) {
        float xjv[DIM];
        #pragma unroll
        for (int d = 0; d < DIM; ++d) xjv[d] = xj_s[jj][d];  // broadcast reads
        float dot = 0.0f;
        #pragma unroll
        for (int d = 0; d < DIM; ++d) dot = fmaf(xi[d], xjv[d], dot);
        float d2 = fmaxf(fmaf(-2.0f, dot, sqi + sq_s[jj]), 0.0f);
        bool hot = (d2 < 25.0f) && (ci > c_s[jj]);
        if (__any(hot)) {     // wave-uniform; almost always false
            float w = hot ? exp2f(fmaf(-1.4426950408889634f, d2, 1.0f)) : 0.0f;
            wsum += w;
            #pragma unroll
            for (int d = 0; d < DIM; ++d) acc[d] = fmaf(w, xjv[d], acc[d]);
        }
    }

    const size_t base = ((size_t)blockIdx.y * NSI + (size_t)s * POP + i) * NCOMP;
    #pragma unroll
    for (int d = 0; d < DIM; ++d) partial[base + d] = acc[d];
    partial[base + 16] = wsum;
}

// ---- reduce partials + update + clip + mix + next-step cost ---------------
__global__ void update_kernel(const float* __restrict__ xin,
                              const float* __restrict__ partial,
                              const float* __restrict__ noise_step,
                              float alpha, int mix, int jchunks,
                              float* __restrict__ xout,
                              float* __restrict__ sq, float* __restrict__ cost) {
    int t  = blockIdx.x * blockDim.x + threadIdx.x;   // NSI*DIM threads
    int si = t >> 4;
    int d  = t & 15;
    int s  = si >> 12;          // / POP
    int i  = si & (POP - 1);

    float asum = 0.0f, wsum = 0.0f;
    for (int jc = 0; jc < jchunks; ++jc) {
        size_t b = ((size_t)jc * NSI + si) * NCOMP;
        asum += partial[b + d];
        wsum += partial[b + 16];
    }

    float xv = xin[t];
    float nz = noise_step[t];
    float xn = xv + asum - wsum * xv + alpha * (nz - 0.5f) * 8.0f;
    xn = fminf(fmaxf(xn, -4.0f), 4.0f);

    int s_out  = (mix && i >= POP / 2) ? ((s + 1) & (SPECIES - 1)) : s;
    int outsi  = s_out * POP + i;
    xout[(size_t)outsi * DIM + d] = xn;

    // cost/sq of the new position, written at the (possibly mixed) location
    float s1 = xn * xn;
    float c  = cospif(2.0f * xn);
    float s1t = seg16_sum(s1);
    float ct  = seg16_sum(c);
    if (d == 0) {
        sq[outsi]   = s1t;
        cost[outsi] = 10.0f * DIM + s1t - 10.0f * ct;
    }
}

extern "C" void kernel_launch(void* const* d_in, const int* in_sizes, int n_in,
                              void* d_out, int out_size, void* d_ws, size_t ws_size,
                              hipStream_t stream) {
    const float* x0    = (const float*)d_in[0];
    const float* noise = (const float*)d_in[1];
    const int steps = in_sizes[1] / in_sizes[0];      // = 4

    float* f       = (float*)d_ws;
    float* xA      = f;
    float* xB      = f + (size_t)NSI * DIM;
    float* sq      = f + (size_t)2 * NSI * DIM;
    float* cost    = sq + NSI;
    float* partial = cost + NSI;

    // pick j-chunk count by workspace size (partial = JC*NSI*NCOMP floats)
    size_t fixed_floats = (size_t)2 * NSI * DIM + 2 * NSI;
    size_t avail = ws_size / sizeof(float) > fixed_floats
                 ? ws_size / sizeof(float) - fixed_floats : 0;
    const bool big = avail >= (size_t)16 * NSI * NCOMP;
    const int JC = big ? 16 : 8;

    cost_kernel<<<(NSI * DIM) / 256, 256, 0, stream>>>(x0, sq, cost);

    const float* xin = x0;
    float alpha = 0.1f;
    float* bufs[2] = {xA, xB};
    int bi = 0;
    for (int step = 0; step < steps; ++step) {
        if (big)
            pair_kernel<16><<<dim3(POP / ITILE, 16, SPECIES), 256, 0, stream>>>(
                xin, sq, cost, partial);
        else
            pair_kernel<8><<<dim3(POP / ITILE, 8, SPECIES), 256, 0, stream>>>(
                xin, sq, cost, partial);

        float* xout = (step == steps - 1) ? (float*)d_out : bufs[bi];
        int mix = (step % 25 == 0) ? 1 : 0;
        update_kernel<<<(NSI * DIM) / 256, 256, 0, stream>>>(
            xin, partial, noise + (size_t)step * NSI * DIM,
            alpha, mix, JC, xout, sq, cost);

        xin = xout;
        bi ^= 1;
        alpha *= 0.995f;
    }
}

// Round 2
// 186.296 us; speedup vs baseline: 1.6133x; 1.6133x over previous
//
#include <hip/hip_runtime.h>

// Firefly optimizer, round 2: MFMA Gram-matrix gating.
// d2 = sqi + sqj - 2*g where g = <xi,xj> comes from ONE v_mfma_f32_32x32x16_bf16
// per 32x32 pair tile (K=16 exactly). The threshold test d2 < T is folded into
// the MFMA C operand: D = g + (T - sqi - sqj)/2 > 0. Hot elements (rare; incl.
// the forced diagonal d2=0 which the cost mask rejects) take an exact-fp32
// slow path with atomicAdd into attr[]. bf16 only gates the threshold; w is
// always computed from exact fp32 d2, so numerics match round 1 (~1e-3 absmax).

#define SPECIES 4
#define POP     4096
#define DIM     16
#define NSI     (SPECIES * POP)
#define T_CUT   14.0f     // w = 2exp(-14) = 1.7e-6; skipped-pair error << 8e-2
#define JC      8         // j-chunks in pair grid

typedef __attribute__((ext_vector_type(8)))  short short8;    // 8 bf16 (4 VGPR)
typedef __attribute__((ext_vector_type(16))) float floatx16;  // MFMA C/D

__device__ __forceinline__ unsigned short f2bf(float f) {
    unsigned u = __float_as_uint(f);
    u += 0x7FFFu + ((u >> 16) & 1u);       // round-to-nearest-even
    return (unsigned short)(u >> 16);
}

__device__ __forceinline__ float seg16_sum(float v) {
    v += __shfl_xor(v, 1, 16);
    v += __shfl_xor(v, 2, 16);
    v += __shfl_xor(v, 4, 16);
    v += __shfl_xor(v, 8, 16);
    return v;
}

// ---- init: x0 -> xb (bf16), sq, cost; zero attr ---------------------------
__global__ void init_kernel(const float* __restrict__ x,
                            unsigned short* __restrict__ xb,
                            float* __restrict__ sq, float* __restrict__ cost,
                            float* __restrict__ attr) {
    int t  = blockIdx.x * blockDim.x + threadIdx.x;   // NSI*DIM
    int si = t >> 4;
    int d  = t & 15;
    attr[t] = 0.0f;
    float xv = x[t];
    xb[t] = f2bf(xv);
    float s1t = seg16_sum(xv * xv);
    float ct  = seg16_sum(cospif(2.0f * xv));
    if (d == 0) {
        sq[si]   = s1t;
        cost[si] = 10.0f * DIM + s1t - 10.0f * ct;
    }
}

// ---- pairwise gate via MFMA -----------------------------------------------
// grid (POP/128, JC, SPECIES), block 256 = 4 waves; wave handles 32 i's.
__global__ __launch_bounds__(256) void pair_kernel(
        const unsigned short* __restrict__ xb,   // bf16 bits [NSI][DIM]
        const float* __restrict__ x,             // fp32 positions
        const float* __restrict__ sq,
        const float* __restrict__ cost,
        float* __restrict__ attr) {
    const int lane = threadIdx.x & 63;
    const int wave = threadIdx.x >> 6;
    const int l31  = lane & 31;
    const int half = lane >> 5;
    const int s    = blockIdx.z;
    const int sb   = s * POP;
    const int i0   = blockIdx.x * 128 + wave * 32;
    const int j0   = blockIdx.y * (POP / JC);

    // A fragment: A[m=l31][k=half*8 + 0..7], 16B contiguous per lane
    const short8* ap = (const short8*)(xb + (size_t)(sb + i0) * DIM);
    const short8  afrag = ap[(l31 << 1) | half];

    // per-reg row r = (reg&3) + 8*(reg>>2) + 4*half; precompute (T - sqi)/2
    float nai[16];
    {
        const float* sqi = sq + sb + i0 + 4 * half;
        #pragma unroll
        for (int b = 0; b < 4; ++b) {
            float4 v = *(const float4*)(sqi + 8 * b);
            nai[4 * b + 0] = 0.5f * (T_CUT - v.x);
            nai[4 * b + 1] = 0.5f * (T_CUT - v.y);
            nai[4 * b + 2] = 0.5f * (T_CUT - v.z);
            nai[4 * b + 3] = 0.5f * (T_CUT - v.w);
        }
    }

    const short8* bp  = (const short8*)(xb + (size_t)(sb + j0) * DIM);
    const float*  sqj = sq + sb + j0;

    #pragma unroll 2
    for (int jt = 0; jt < POP / JC; jt += 32) {
        // B fragment: B[k][n=l31] = xj[n][k] — same load pattern as A (Gram)
        short8 bfrag = bp[((jt + l31) << 1) | half];
        float  bjh   = -0.5f * sqj[jt + l31];
        floatx16 c;
        #pragma unroll
        for (int r = 0; r < 16; ++r) c[r] = nai[r] + bjh;
        floatx16 d = __builtin_amdgcn_mfma_f32_32x32x16_bf16(afrag, bfrag, c,
                                                             0, 0, 0);
        unsigned long long any = 0;
        #pragma unroll
        for (int r = 0; r < 16; ++r) any |= __ballot(d[r] > 0.0f);

        if (any) {   // rare: close pair candidates (or forced diagonal d2=0)
            const int j = j0 + jt + l31;
            #pragma unroll 1
            for (int r = 0; r < 16; ++r) {
                if (d[r] > 0.0f) {
                    const int i = i0 + (r & 3) + 8 * (r >> 2) + 4 * half;
                    const float* xi = x + (size_t)(sb + i) * DIM;
                    const float* xj = x + (size_t)(sb + j) * DIM;
                    float dot = 0.0f;
                    #pragma unroll
                    for (int dd = 0; dd < 16; ++dd)
                        dot = fmaf(xi[dd], xj[dd], dot);
                    float d2 = fmaxf(fmaf(-2.0f, dot,
                                          sq[sb + i] + sq[sb + j]), 0.0f);
                    if (d2 < T_CUT && cost[sb + i] > cost[sb + j]) {
                        float w = 2.0f * expf(-d2);
                        #pragma unroll
                        for (int dd = 0; dd < 16; ++dd)
                            atomicAdd(&attr[(size_t)(sb + i) * DIM + dd],
                                      w * (xj[dd] - xi[dd]));
                    }
                }
            }
        }
    }
}

// ---- update + clip + mix + next-step bf16/sq/cost; zero attr in place -----
__global__ void update_kernel(const float* __restrict__ xin,
                              const float* __restrict__ noise_step,
                              float* __restrict__ attr,
                              float alpha, int mix,
                              float* __restrict__ xout,
                              unsigned short* __restrict__ xb,
                              float* __restrict__ sq, float* __restrict__ cost) {
    int t  = blockIdx.x * blockDim.x + threadIdx.x;   // NSI*DIM
    int si = t >> 4;
    int d  = t & 15;
    int s  = si >> 12;
    int i  = si & (POP - 1);

    float a = attr[t];
    attr[t] = 0.0f;                                   // ready for next step
    float xv = xin[t];
    float nz = noise_step[t];
    float xn = xv + a + alpha * (nz - 0.5f) * 8.0f;
    xn = fminf(fmaxf(xn, -4.0f), 4.0f);

    int s_out = (mix && i >= POP / 2) ? ((s + 1) & (SPECIES - 1)) : s;
    int outsi = s_out * POP + i;
    size_t ot = (size_t)outsi * DIM + d;
    xout[ot] = xn;
    xb[ot]   = f2bf(xn);

    float s1t = seg16_sum(xn * xn);
    float ct  = seg16_sum(cospif(2.0f * xn));
    if (d == 0) {
        sq[outsi]   = s1t;
        cost[outsi] = 10.0f * DIM + s1t - 10.0f * ct;
    }
}

extern "C" void kernel_launch(void* const* d_in, const int* in_sizes, int n_in,
                              void* d_out, int out_size, void* d_ws, size_t ws_size,
                              hipStream_t stream) {
    const float* x0    = (const float*)d_in[0];
    const float* noise = (const float*)d_in[1];
    const int steps = in_sizes[1] / in_sizes[0];      // = 4

    float* f    = (float*)d_ws;
    float* xA   = f;                                  // NSI*DIM
    float* xB   = xA + (size_t)NSI * DIM;             // NSI*DIM
    float* attr = xB + (size_t)NSI * DIM;             // NSI*DIM
    float* sq   = attr + (size_t)NSI * DIM;           // NSI
    float* cost = sq + NSI;                           // NSI
    unsigned short* xb = (unsigned short*)(cost + NSI);  // NSI*DIM bf16

    init_kernel<<<(NSI * DIM) / 256, 256, 0, stream>>>(x0, xb, sq, cost, attr);

    const float* xin = x0;
    float alpha = 0.1f;
    float* bufs[2] = {xA, xB};
    int bi = 0;
    for (int step = 0; step < steps; ++step) {
        pair_kernel<<<dim3(POP / 128, JC, SPECIES), 256, 0, stream>>>(
            xb, xin, sq, cost, attr);

        float* xout = (step == steps - 1) ? (float*)d_out : bufs[bi];
        int mix = (step % 25 == 0) ? 1 : 0;
        update_kernel<<<(NSI * DIM) / 256, 256, 0, stream>>>(
            xin, noise + (size_t)step * NSI * DIM, attr,
            alpha, mix, xout, xb, sq, cost);

        xin = xout;
        bi ^= 1;
        alpha *= 0.995f;
    }
}

// Round 3
// 159.496 us; speedup vs baseline: 1.8843x; 1.1680x over previous
//
#include <hip/hip_runtime.h>

// Firefly optimizer, round 3.
// R2 post-mortem: slow path (exact fp32 recompute + atomics) fired on ~25% of
// 32x32 tiles (P(d2<14) ~ 3e-4 per pair => ~1e5 hot pairs/step) and dominated.
// Fixes: (1) T 14->10: hot rate ~T^8 => 15x fewer entries; skipped pairs have
// w <= 9e-5 => ~1e-3 added error vs 8e-2 threshold. (2) C operand is now the
// loop-invariant (T-sqi)/2 and the per-tile gate is max16(D) > sqj/2 -- one
// fmax tree + one cmp instead of 16 adds + 16 ballots per iteration.

#define SPECIES 4
#define POP     4096
#define DIM     16
#define NSI     (SPECIES * POP)
#define T_CUT   10.0f
#define JC      16        // j-chunks: grid (32,16,4) = 2048 blocks, 32 waves/CU

typedef __attribute__((ext_vector_type(8)))  short short8;    // 8 bf16 (4 VGPR)
typedef __attribute__((ext_vector_type(16))) float floatx16;  // MFMA C/D

__device__ __forceinline__ unsigned short f2bf(float f) {
    unsigned u = __float_as_uint(f);
    u += 0x7FFFu + ((u >> 16) & 1u);       // round-to-nearest-even
    return (unsigned short)(u >> 16);
}

__device__ __forceinline__ float seg16_sum(float v) {
    v += __shfl_xor(v, 1, 16);
    v += __shfl_xor(v, 2, 16);
    v += __shfl_xor(v, 4, 16);
    v += __shfl_xor(v, 8, 16);
    return v;
}

// ---- init: x0 -> xb (bf16), sq, cost; zero attr ---------------------------
__global__ void init_kernel(const float* __restrict__ x,
                            unsigned short* __restrict__ xb,
                            float* __restrict__ sq, float* __restrict__ cost,
                            float* __restrict__ attr) {
    int t  = blockIdx.x * blockDim.x + threadIdx.x;   // NSI*DIM
    int si = t >> 4;
    int d  = t & 15;
    attr[t] = 0.0f;
    float xv = x[t];
    xb[t] = f2bf(xv);
    float s1t = seg16_sum(xv * xv);
    float ct  = seg16_sum(cospif(2.0f * xv));
    if (d == 0) {
        sq[si]   = s1t;
        cost[si] = 10.0f * DIM + s1t - 10.0f * ct;
    }
}

// ---- pairwise gate via MFMA -----------------------------------------------
// grid (POP/128, JC, SPECIES), block 256 = 4 waves; wave handles 32 i's.
// D[r][lane] = <xi_r, xj_lane> + (T - sq_i(r))/2 ; hot  <=>  D > sqj/2.
__global__ __launch_bounds__(256) void pair_kernel(
        const unsigned short* __restrict__ xb,   // bf16 bits [NSI][DIM]
        const float* __restrict__ x,             // fp32 positions
        const float* __restrict__ sq,
        const float* __restrict__ cost,
        float* __restrict__ attr) {
    const int lane = threadIdx.x & 63;
    const int wave = threadIdx.x >> 6;
    const int l31  = lane & 31;
    const int half = lane >> 5;
    const int s    = blockIdx.z;
    const int sb   = s * POP;
    const int i0   = blockIdx.x * 128 + wave * 32;
    const int j0   = blockIdx.y * (POP / JC);

    // A fragment: A[m=l31][k=half*8 + 0..7]
    const short8* ap = (const short8*)(xb + (size_t)(sb + i0) * DIM);
    const short8  afrag = ap[(l31 << 1) | half];

    // loop-invariant C: row r = (r&3) + 8*(r>>2) + 4*half
    floatx16 c;
    {
        const float* sqi = sq + sb + i0 + 4 * half;
        #pragma unroll
        for (int b = 0; b < 4; ++b) {
            float4 v = *(const float4*)(sqi + 8 * b);
            c[4 * b + 0] = 0.5f * (T_CUT - v.x);
            c[4 * b + 1] = 0.5f * (T_CUT - v.y);
            c[4 * b + 2] = 0.5f * (T_CUT - v.z);
            c[4 * b + 3] = 0.5f * (T_CUT - v.w);
        }
    }

    const short8* bp  = (const short8*)(xb + (size_t)(sb + j0) * DIM);
    const float*  sqj = sq + sb + j0;

    #pragma unroll 2
    for (int jt = 0; jt < POP / JC; jt += 32) {
        short8 bfrag = bp[((jt + l31) << 1) | half];
        float  hsqj  = 0.5f * sqj[jt + l31];
        floatx16 d = __builtin_amdgcn_mfma_f32_32x32x16_bf16(afrag, bfrag, c,
                                                             0, 0, 0);
        // max over the 16 rows (folds to v_max3 tree), one compare per lane
        float m0 = fmaxf(fmaxf(d[0], d[1]),  fmaxf(d[2], d[3]));
        float m1 = fmaxf(fmaxf(d[4], d[5]),  fmaxf(d[6], d[7]));
        float m2 = fmaxf(fmaxf(d[8], d[9]),  fmaxf(d[10], d[11]));
        float m3 = fmaxf(fmaxf(d[12], d[13]), fmaxf(d[14], d[15]));
        float m  = fmaxf(fmaxf(m0, m1), fmaxf(m2, m3));

        if (__any(m > hsqj)) {   // ~1% of tiles (incl. forced diagonal d2=0)
            const int j = j0 + jt + l31;
            #pragma unroll 1
            for (int r = 0; r < 16; ++r) {
                if (d[r] > hsqj) {
                    const int i = i0 + (r & 3) + 8 * (r >> 2) + 4 * half;
                    const float* xi = x + (size_t)(sb + i) * DIM;
                    const float* xj = x + (size_t)(sb + j) * DIM;
                    float dot = 0.0f;
                    #pragma unroll
                    for (int dd = 0; dd < 16; ++dd)
                        dot = fmaf(xi[dd], xj[dd], dot);
                    float d2 = fmaxf(fmaf(-2.0f, dot,
                                          sq[sb + i] + sq[sb + j]), 0.0f);
                    if (d2 < T_CUT && cost[sb + i] > cost[sb + j]) {
                        float w = 2.0f * expf(-d2);
                        #pragma unroll
                        for (int dd = 0; dd < 16; ++dd)
                            atomicAdd(&attr[(size_t)(sb + i) * DIM + dd],
                                      w * (xj[dd] - xi[dd]));
                    }
                }
            }
        }
    }
}

// ---- update + clip + mix + next-step bf16/sq/cost; zero attr in place -----
__global__ void update_kernel(const float* __restrict__ xin,
                              const float* __restrict__ noise_step,
                              float* __restrict__ attr,
                              float alpha, int mix,
                              float* __restrict__ xout,
                              unsigned short* __restrict__ xb,
                              float* __restrict__ sq, float* __restrict__ cost) {
    int t  = blockIdx.x * blockDim.x + threadIdx.x;   // NSI*DIM
    int si = t >> 4;
    int d  = t & 15;
    int s  = si >> 12;
    int i  = si & (POP - 1);

    float a = attr[t];
    attr[t] = 0.0f;                                   // ready for next step
    float xv = xin[t];
    float nz = noise_step[t];
    float xn = xv + a + alpha * (nz - 0.5f) * 8.0f;
    xn = fminf(fmaxf(xn, -4.0f), 4.0f);

    int s_out = (mix && i >= POP / 2) ? ((s + 1) & (SPECIES - 1)) : s;
    int outsi = s_out * POP + i;
    size_t ot = (size_t)outsi * DIM + d;
    xout[ot] = xn;
    xb[ot]   = f2bf(xn);

    float s1t = seg16_sum(xn * xn);
    float ct  = seg16_sum(cospif(2.0f * xn));
    if (d == 0) {
        sq[outsi]   = s1t;
        cost[outsi] = 10.0f * DIM + s1t - 10.0f * ct;
    }
}

extern "C" void kernel_launch(void* const* d_in, const int* in_sizes, int n_in,
                              void* d_out, int out_size, void* d_ws, size_t ws_size,
                              hipStream_t stream) {
    const float* x0    = (const float*)d_in[0];
    const float* noise = (const float*)d_in[1];
    const int steps = in_sizes[1] / in_sizes[0];      // = 4

    float* f    = (float*)d_ws;
    float* xA   = f;                                  // NSI*DIM
    float* xB   = xA + (size_t)NSI * DIM;             // NSI*DIM
    float* attr = xB + (size_t)NSI * DIM;             // NSI*DIM
    float* sq   = attr + (size_t)NSI * DIM;           // NSI
    float* cost = sq + NSI;                           // NSI
    unsigned short* xb = (unsigned short*)(cost + NSI);  // NSI*DIM bf16

    init_kernel<<<(NSI * DIM) / 256, 256, 0, stream>>>(x0, xb, sq, cost, attr);

    const float* xin = x0;
    float alpha = 0.1f;
    float* bufs[2] = {xA, xB};
    int bi = 0;
    for (int step = 0; step < steps; ++step) {
        pair_kernel<<<dim3(POP / 128, JC, SPECIES), 256, 0, stream>>>(
            xb, xin, sq, cost, attr);

        float* xout = (step == steps - 1) ? (float*)d_out : bufs[bi];
        int mix = (step % 25 == 0) ? 1 : 0;
        update_kernel<<<(NSI * DIM) / 256, 256, 0, stream>>>(
            xin, noise + (size_t)step * NSI * DIM, attr,
            alpha, mix, xout, xb, sq, cost);

        xin = xout;
        bi ^= 1;
        alpha *= 0.995f;
    }
}